// Round 1
// baseline (415.716 us; speedup 1.0000x reference)
//
#include <hip/hip_runtime.h>
#include <math.h>

#define BB 32
#define PP 8732
#define MM 16
#define NC 81
#define THRESH 0.5f
#define NPR 3

// ---------------------------------------------------------------------------
// Kernel A: per-image matching.
// One block per image. Computes per-prior best overlap + object (first-occurrence
// argmax), per-object best prior (first-occurrence argmax across P), then the
// force-match scatter (m ascending => last write wins, matching numpy/CPU-XLA).
// ---------------------------------------------------------------------------
__global__ void __launch_bounds__(256) match_kernel(
    const float* __restrict__ boxes,   // [B,M,4] xy
    const float* __restrict__ priors,  // [P,4] cxcy
    float* __restrict__ ovl,           // [B,P]
    int* __restrict__ obj)             // [B,P]
{
    const int b = blockIdx.x;
    const int tid = threadIdx.x;
    __shared__ float s_box[MM][4];
    __shared__ float s_area[MM];
    __shared__ float s_bv[4 * MM];
    __shared__ int   s_bi[4 * MM];

    if (tid < MM * 4) ((float*)s_box)[tid] = boxes[b * MM * 4 + tid];
    __syncthreads();
    if (tid < MM)
        s_area[tid] = (s_box[tid][2] - s_box[tid][0]) * (s_box[tid][3] - s_box[tid][1]);
    __syncthreads();

    float bestv[MM];
    int   bestp[MM];
#pragma unroll
    for (int m = 0; m < MM; ++m) { bestv[m] = -1.0f; bestp[m] = 0; }

    for (int p = tid; p < PP; p += blockDim.x) {
        float pcx = priors[p * 4 + 0], pcy = priors[p * 4 + 1];
        float pw  = priors[p * 4 + 2], ph  = priors[p * 4 + 3];
        float px0 = pcx - pw * 0.5f, py0 = pcy - ph * 0.5f;
        float px1 = pcx + pw * 0.5f, py1 = pcy + ph * 0.5f;
        float parea = (px1 - px0) * (py1 - py0);
        float bv = -1.0f; int bm = 0;
#pragma unroll
        for (int m = 0; m < MM; ++m) {
            float lx = fmaxf(s_box[m][0], px0);
            float ly = fmaxf(s_box[m][1], py0);
            float rx = fminf(s_box[m][2], px1);
            float ry = fminf(s_box[m][3], py1);
            float w = fmaxf(rx - lx, 0.0f);
            float h = fmaxf(ry - ly, 0.0f);
            float inter = w * h;
            float iou = inter / (s_area[m] + parea - inter);
            if (iou > bv) { bv = iou; bm = m; }                      // first-occurrence over m
            if (iou > bestv[m]) { bestv[m] = iou; bestp[m] = p; }    // first-occurrence over p (p ascending per thread)
        }
        ovl[b * PP + p] = bv;
        obj[b * PP + p] = bm;
    }

    const int lane = tid & 63, wid = tid >> 6;
#pragma unroll
    for (int m = 0; m < MM; ++m) {
        float v = bestv[m]; int i = bestp[m];
        for (int off = 32; off > 0; off >>= 1) {
            float ov = __shfl_xor(v, off);
            int   oi = __shfl_xor(i, off);
            if (ov > v || (ov == v && oi < i)) { v = ov; i = oi; }
        }
        if (lane == 0) { s_bv[wid * MM + m] = v; s_bi[wid * MM + m] = i; }
    }
    __syncthreads();   // also makes this block's global ovl/obj writes visible

    if (tid == 0) {
        for (int m = 0; m < MM; ++m) {    // m ascending: duplicate priors -> last wins
            float v = s_bv[m]; int i = s_bi[m];
            for (int w = 1; w < 4; ++w) {
                float ov = s_bv[w * MM + m]; int oi = s_bi[w * MM + m];
                if (ov > v || (ov == v && oi < i)) { v = ov; i = oi; }
            }
            obj[b * PP + i] = m;
            ovl[b * PP + i] = 1.0f;
        }
    }
}

// ---------------------------------------------------------------------------
// Kernel B: one wave per (b,p) row. log-softmax CE over 81 classes, positive
// accumulation (atomics, rare), negative CE stored for hard-negative mining.
// ---------------------------------------------------------------------------
__global__ void __launch_bounds__(256) conf_kernel(
    const float* __restrict__ logits,  // [B,P,81]
    const float* __restrict__ plocs,   // [B,P,4]
    const float* __restrict__ boxes,   // [B,M,4] xy
    const int*   __restrict__ labels,  // [B,M]
    const float* __restrict__ priors,  // [P,4] cxcy
    const float* __restrict__ ovl,     // [B,P]
    const int*   __restrict__ obj,     // [B,P]
    float* __restrict__ neg,           // [B,P]
    int*   __restrict__ npos,          // [B]
    float* __restrict__ totals)        // [0]=pos conf sum, [1]=loc L1 sum
{
    const int wave = blockIdx.x * (blockDim.x >> 6) + (threadIdx.x >> 6);
    const int lane = threadIdx.x & 63;
    if (wave >= BB * PP) return;
    const int b = wave / PP;
    const int p = wave - b * PP;

    const size_t base = (size_t)wave * NC;
    float e0 = logits[base + lane];
    float e1 = (lane < NC - 64) ? logits[base + 64 + lane] : -INFINITY;

    float mx = fmaxf(e0, e1);
    for (int off = 32; off > 0; off >>= 1) mx = fmaxf(mx, __shfl_xor(mx, off));
    float s = __expf(e0 - mx) + ((lane < NC - 64) ? __expf(e1 - mx) : 0.0f);
    for (int off = 32; off > 0; off >>= 1) s += __shfl_xor(s, off);

    const float ov = ovl[wave];
    const int o = obj[wave];
    const int cls = (ov < THRESH) ? 0 : labels[b * MM + o];

    float xc = (cls < 64) ? __shfl(e0, cls) : __shfl(e1, cls - 64);
    float conf = mx + __logf(s) - xc;
    if (!isfinite(conf)) conf = 0.0f;

    if (lane == 0) {
        neg[wave] = (cls == 0) ? conf : 0.0f;
        if (cls != 0) {
            atomicAdd(&npos[b], 1);
            atomicAdd(&totals[0], conf);
            const float* bx = &boxes[(b * MM + o) * 4];
            float cx = (bx[0] + bx[2]) * 0.5f;
            float cy = (bx[1] + bx[3]) * 0.5f;
            float w  = bx[2] - bx[0];
            float h  = bx[3] - bx[1];
            float pcx = priors[p * 4 + 0], pcy = priors[p * 4 + 1];
            float pw  = priors[p * 4 + 2], ph  = priors[p * 4 + 3];
            float g0 = (cx - pcx) / (pw / 10.0f);
            float g1 = (cy - pcy) / (ph / 10.0f);
            float g2 = logf(w / pw) * 5.0f;
            float g3 = logf(h / ph) * 5.0f;
            const float* pl = &plocs[(size_t)wave * 4];
            float l1 = fabsf(pl[0] - g0) + fabsf(pl[1] - g1) +
                       fabsf(pl[2] - g2) + fabsf(pl[3] - g3);
            atomicAdd(&totals[1], l1);
        }
    }
}

// ---------------------------------------------------------------------------
// Kernel C: per-image exact top-K sum of negative CE via binary search on the
// (nonnegative => monotonic) float bit pattern. Array staged in LDS.
// ---------------------------------------------------------------------------
__device__ __forceinline__ int block_reduce_int(int v, int* s4, int tid) {
    for (int off = 32; off > 0; off >>= 1) v += __shfl_xor(v, off);
    if ((tid & 63) == 0) s4[tid >> 6] = v;
    __syncthreads();
    int total = s4[0] + s4[1] + s4[2] + s4[3];
    __syncthreads();
    return total;
}

__global__ void __launch_bounds__(256) topk_kernel(
    const float* __restrict__ neg, const int* __restrict__ npos,
    float* __restrict__ hardneg)
{
    const int b = blockIdx.x;
    const int tid = threadIdx.x;
    __shared__ unsigned s_bits[PP];
    __shared__ int s4i[4];
    __shared__ float s4f[4];

    for (int p = tid; p < PP; p += blockDim.x)
        s_bits[p] = __float_as_uint(neg[b * PP + p]);
    __syncthreads();

    long long K = (long long)NPR * (long long)npos[b];
    if (K > PP) K = PP;
    if (K <= 0) { if (tid == 0) hardneg[b] = 0.0f; return; }

    unsigned lo = 0u, hi = 0x7fffffffu;
    while (lo < hi) {
        unsigned mid = lo + ((hi - lo + 1u) >> 1);
        int cnt = 0;
        for (int p = tid; p < PP; p += blockDim.x) cnt += (s_bits[p] >= mid);
        int total = block_reduce_int(cnt, s4i, tid);
        if (total >= K) lo = mid; else hi = mid - 1u;
    }
    const unsigned kth = lo;

    int cgt = 0; float sgt = 0.0f;
    for (int p = tid; p < PP; p += blockDim.x) {
        unsigned u = s_bits[p];
        if (u > kth) { cgt++; sgt += __uint_as_float(u); }
    }
    int cgt_t = block_reduce_int(cgt, s4i, tid);
    for (int off = 32; off > 0; off >>= 1) sgt += __shfl_xor(sgt, off);
    if ((tid & 63) == 0) s4f[tid >> 6] = sgt;
    __syncthreads();
    if (tid == 0) {
        float sum_gt = s4f[0] + s4f[1] + s4f[2] + s4f[3];
        hardneg[b] = sum_gt + (float)(K - cgt_t) * __uint_as_float(kth);
    }
}

// ---------------------------------------------------------------------------
// Kernel D: final scalar combine.
// ---------------------------------------------------------------------------
__global__ void final_kernel(const int* __restrict__ npos,
                             const float* __restrict__ hardneg,
                             const float* __restrict__ totals,
                             float* __restrict__ out)
{
    const int tid = threadIdx.x;
    int np = (tid < BB) ? npos[tid] : 0;
    float hn = (tid < BB) ? hardneg[tid] : 0.0f;
    for (int off = 32; off > 0; off >>= 1) {
        np += __shfl_xor(np, off);
        hn += __shfl_xor(hn, off);
    }
    if (tid == 0) {
        float npt = (float)np;
        out[0] = (hn + totals[0]) / npt + totals[1] / (4.0f * npt);
    }
}

extern "C" void kernel_launch(void* const* d_in, const int* in_sizes, int n_in,
                              void* d_out, int out_size, void* d_ws, size_t ws_size,
                              hipStream_t stream) {
    (void)in_sizes; (void)n_in; (void)out_size; (void)ws_size;
    const float* plocs  = (const float*)d_in[0];
    const float* logits = (const float*)d_in[1];
    const float* boxes  = (const float*)d_in[2];
    const int*   labels = (const int*)d_in[3];
    const float* priors = (const float*)d_in[4];
    float* out = (float*)d_out;

    char* ws = (char*)d_ws;
    float* ovl     = (float*)ws; ws += (size_t)BB * PP * 4;
    int*   obj     = (int*)ws;   ws += (size_t)BB * PP * 4;
    float* neg     = (float*)ws; ws += (size_t)BB * PP * 4;
    int*   npos    = (int*)ws;   ws += BB * 4;
    float* hardneg = (float*)ws; ws += BB * 4;
    float* totals  = (float*)ws; ws += 2 * 4;

    // zero npos + hardneg + totals (contiguous)
    hipMemsetAsync(npos, 0, BB * 4 + BB * 4 + 2 * 4, stream);

    match_kernel<<<BB, 256, 0, stream>>>(boxes, priors, ovl, obj);

    const int waves = BB * PP;
    const int blocksB = (waves + 3) / 4;
    conf_kernel<<<blocksB, 256, 0, stream>>>(logits, plocs, boxes, labels, priors,
                                             ovl, obj, neg, npos, totals);

    topk_kernel<<<BB, 256, 0, stream>>>(neg, npos, hardneg);

    final_kernel<<<1, 64, 0, stream>>>(npos, hardneg, totals, out);
}

// Round 2
// 329.775 us; speedup vs baseline: 1.2606x; 1.2606x over previous
//
#include <hip/hip_runtime.h>
#include <math.h>

#define BB 32
#define PP 8732
#define MM 16
#define NC 81
#define THRESH 0.5f
#define NPR 3
#define CHUNKS 8
#define CHUNK ((PP + CHUNKS - 1) / CHUNKS)   // 1092
#define CONF_BLOCKS 2048

// ---------------------------------------------------------------------------
// Kernel A1: partitioned matching. grid = BB*CHUNKS blocks; block (b,c) handles
// priors [c*CHUNK, ...) of image b: writes per-prior best overlap/object, and
// contributes to per-object best-prior via packed atomicMax key:
//   key = (iou_bits << 32) | (0x7FFFFFFF - p)
// (iou >= 0 so float bits are monotonic; ties on iou -> larger key = smaller p
//  = first-occurrence argmax, matching jnp.argmax.)
// ---------------------------------------------------------------------------
__global__ void __launch_bounds__(256) match_part_kernel(
    const float* __restrict__ boxes,   // [B,M,4] xy
    const float* __restrict__ priors,  // [P,4] cxcy
    float* __restrict__ ovl,           // [B,P]
    int* __restrict__ obj,             // [B,P]
    unsigned long long* __restrict__ keys)  // [B,M]
{
    const int b = blockIdx.x / CHUNKS;
    const int c = blockIdx.x % CHUNKS;
    const int tid = threadIdx.x;
    __shared__ float s_box[MM][4];
    __shared__ float s_area[MM];
    __shared__ float s_bv[4 * MM];
    __shared__ int   s_bi[4 * MM];

    if (tid < MM * 4) ((float*)s_box)[tid] = boxes[b * MM * 4 + tid];
    __syncthreads();
    if (tid < MM)
        s_area[tid] = (s_box[tid][2] - s_box[tid][0]) * (s_box[tid][3] - s_box[tid][1]);
    __syncthreads();

    float bestv[MM];
    int   bestp[MM];
#pragma unroll
    for (int m = 0; m < MM; ++m) { bestv[m] = -1.0f; bestp[m] = 0; }

    const int p0 = c * CHUNK;
    const int p1 = (p0 + CHUNK < PP) ? (p0 + CHUNK) : PP;
    for (int p = p0 + tid; p < p1; p += 256) {
        const float4 pr = ((const float4*)priors)[p];
        float px0 = pr.x - pr.z * 0.5f, py0 = pr.y - pr.w * 0.5f;
        float px1 = pr.x + pr.z * 0.5f, py1 = pr.y + pr.w * 0.5f;
        float parea = (px1 - px0) * (py1 - py0);
        float bv = -1.0f; int bm = 0;
#pragma unroll
        for (int m = 0; m < MM; ++m) {
            float lx = fmaxf(s_box[m][0], px0);
            float ly = fmaxf(s_box[m][1], py0);
            float rx = fminf(s_box[m][2], px1);
            float ry = fminf(s_box[m][3], py1);
            float w = fmaxf(rx - lx, 0.0f);
            float h = fmaxf(ry - ly, 0.0f);
            float inter = w * h;
            float iou = inter / (s_area[m] + parea - inter);
            if (iou > bv) { bv = iou; bm = m; }                   // first occurrence over m
            if (iou > bestv[m]) { bestv[m] = iou; bestp[m] = p; } // p ascending per thread
        }
        ovl[b * PP + p] = bv;
        obj[b * PP + p] = bm;
    }

    const int lane = tid & 63, wid = tid >> 6;
#pragma unroll
    for (int m = 0; m < MM; ++m) {
        float v = bestv[m]; int i = bestp[m];
        for (int off = 32; off > 0; off >>= 1) {
            float ov = __shfl_xor(v, off);
            int   oi = __shfl_xor(i, off);
            if (ov > v || (ov == v && oi < i)) { v = ov; i = oi; }
        }
        if (lane == 0) { s_bv[wid * MM + m] = v; s_bi[wid * MM + m] = i; }
    }
    __syncthreads();

    if (tid == 0) {
        for (int m = 0; m < MM; ++m) {
            float v = s_bv[m]; int i = s_bi[m];
            for (int w = 1; w < 4; ++w) {
                float ov = s_bv[w * MM + m]; int oi = s_bi[w * MM + m];
                if (ov > v || (ov == v && oi < i)) { v = ov; i = oi; }
            }
            if (v < 0.0f) v = 0.0f;  // keep bits nonneg/monotonic
            unsigned long long key =
                ((unsigned long long)__float_as_uint(v) << 32) |
                (unsigned long long)(0x7FFFFFFFu - (unsigned)i);
            atomicMax(&keys[b * MM + m], key);
        }
    }
}

// ---------------------------------------------------------------------------
// Kernel A2: force-match scatter. One thread per image, m ascending so that
// duplicate best-priors resolve last-write-wins (numpy scatter semantics).
// ---------------------------------------------------------------------------
__global__ void force_match_kernel(const unsigned long long* __restrict__ keys,
                                   float* __restrict__ ovl, int* __restrict__ obj)
{
    const int b = threadIdx.x;
    if (b < BB) {
        for (int m = 0; m < MM; ++m) {
            unsigned long long key = keys[b * MM + m];
            int p = (int)(0x7FFFFFFFu - (unsigned)(key & 0xFFFFFFFFull));
            obj[b * PP + p] = m;
            ovl[b * PP + p] = 1.0f;
        }
    }
}

// ---------------------------------------------------------------------------
// Kernel B: grid-stride; 16 lanes per row (4 rows per wave). log-softmax CE,
// positive accumulation via rare atomics, negative CE stored for mining.
// ---------------------------------------------------------------------------
__global__ void __launch_bounds__(256) conf_kernel(
    const float* __restrict__ logits,  // [B,P,81]
    const float* __restrict__ plocs,   // [B,P,4]
    const float* __restrict__ boxes,   // [B,M,4] xy
    const int*   __restrict__ labels,  // [B,M]
    const float* __restrict__ priors,  // [P,4] cxcy
    const float* __restrict__ ovl,     // [B,P]
    const int*   __restrict__ obj,     // [B,P]
    float* __restrict__ neg,           // [B,P]
    int*   __restrict__ npos,          // [B]
    float* __restrict__ totals)        // [0]=pos conf sum, [1]=loc L1 sum
{
    const int tid = threadIdx.x;
    const int lane = tid & 63;
    const int g = lane >> 4;          // row group within wave (0..3)
    const int i = lane & 15;          // lane within group
    const int wid = blockIdx.x * (blockDim.x >> 6) + (tid >> 6);
    const int nw = CONF_BLOCKS * 4;
    const int NW_TOT = (BB * PP) / 4;  // 69856 (exact)

    for (int w = wid; w < NW_TOT; w += nw) {
        const int r = w * 4 + g;                 // global row
        const size_t base = (size_t)r * NC;
        float e0 = logits[base + i];
        float e1 = logits[base + 16 + i];
        float e2 = logits[base + 32 + i];
        float e3 = logits[base + 48 + i];
        float e4 = logits[base + 64 + i];
        float e5 = (i == 0) ? logits[base + 80] : -INFINITY;

        float mx = fmaxf(fmaxf(fmaxf(e0, e1), fmaxf(e2, e3)), fmaxf(e4, e5));
#pragma unroll
        for (int off = 8; off > 0; off >>= 1) mx = fmaxf(mx, __shfl_xor(mx, off));
        float s = __expf(e0 - mx) + __expf(e1 - mx) + __expf(e2 - mx) +
                  __expf(e3 - mx) + __expf(e4 - mx) +
                  ((i == 0) ? __expf(e5 - mx) : 0.0f);
#pragma unroll
        for (int off = 8; off > 0; off >>= 1) s += __shfl_xor(s, off);

        const float ov = ovl[r];
        const int o = obj[r];
        const int b = r / PP;
        const int cls = (ov < THRESH) ? 0 : labels[b * MM + o];

        const int k = cls >> 4, ci = cls & 15;   // cls==80 -> k=5, ci=0 (lane 0 holds e5)
        float ek = (k == 0) ? e0 : (k == 1) ? e1 : (k == 2) ? e2 :
                   (k == 3) ? e3 : (k == 4) ? e4 : e5;
        float xc = __shfl(ek, (g << 4) + ci);
        float conf = mx + __logf(s) - xc;
        if (!isfinite(conf)) conf = 0.0f;

        if (i == 0) {
            neg[r] = (cls == 0) ? conf : 0.0f;
            if (cls != 0) {
                atomicAdd(&npos[b], 1);
                atomicAdd(&totals[0], conf);
                const int p = r - b * PP;
                const float4 bx = ((const float4*)boxes)[b * MM + o];
                float cx = (bx.x + bx.z) * 0.5f;
                float cy = (bx.y + bx.w) * 0.5f;
                float w4 = bx.z - bx.x;
                float h4 = bx.w - bx.y;
                const float4 pr = ((const float4*)priors)[p];
                float g0 = (cx - pr.x) / (pr.z / 10.0f);
                float g1 = (cy - pr.y) / (pr.w / 10.0f);
                float g2 = logf(w4 / pr.z) * 5.0f;
                float g3 = logf(h4 / pr.w) * 5.0f;
                const float4 pl = ((const float4*)plocs)[r];
                float l1 = fabsf(pl.x - g0) + fabsf(pl.y - g1) +
                           fabsf(pl.z - g2) + fabsf(pl.w - g3);
                atomicAdd(&totals[1], l1);
            }
        }
    }
}

// ---------------------------------------------------------------------------
// Kernel C: per-image exact top-K sum of negative CE via binary search on the
// (nonnegative => monotonic) float bit pattern. 1024 threads, array in LDS.
// ---------------------------------------------------------------------------
__global__ void __launch_bounds__(1024) topk_kernel(
    const float* __restrict__ neg, const int* __restrict__ npos,
    float* __restrict__ hardneg)
{
    const int b = blockIdx.x;
    const int tid = threadIdx.x;
    const int lane = tid & 63, wid = tid >> 6;
    __shared__ unsigned s_bits[PP];
    __shared__ int s16i[16];
    __shared__ float s16f[16];

    for (int p = tid; p < PP; p += 1024)
        s_bits[p] = __float_as_uint(neg[b * PP + p]);
    __syncthreads();

    long long K = (long long)NPR * (long long)npos[b];
    if (K > PP) K = PP;
    if (K <= 0) { if (tid == 0) hardneg[b] = 0.0f; return; }

    unsigned lo = 0u, hi = 0x7fffffffu;
    while (lo < hi) {
        unsigned mid = lo + ((hi - lo + 1u) >> 1);
        int cnt = 0;
        for (int p = tid; p < PP; p += 1024) cnt += (s_bits[p] >= mid);
        for (int off = 32; off > 0; off >>= 1) cnt += __shfl_xor(cnt, off);
        if (lane == 0) s16i[wid] = cnt;
        __syncthreads();
        int total = 0;
#pragma unroll
        for (int j = 0; j < 16; ++j) total += s16i[j];
        __syncthreads();
        if (total >= K) lo = mid; else hi = mid - 1u;
    }
    const unsigned kth = lo;

    int cgt = 0; float sgt = 0.0f;
    for (int p = tid; p < PP; p += 1024) {
        unsigned u = s_bits[p];
        if (u > kth) { cgt++; sgt += __uint_as_float(u); }
    }
    for (int off = 32; off > 0; off >>= 1) {
        cgt += __shfl_xor(cgt, off);
        sgt += __shfl_xor(sgt, off);
    }
    if (lane == 0) { s16i[wid] = cgt; s16f[wid] = sgt; }
    __syncthreads();
    if (tid == 0) {
        int cgt_t = 0; float sum_gt = 0.0f;
#pragma unroll
        for (int j = 0; j < 16; ++j) { cgt_t += s16i[j]; sum_gt += s16f[j]; }
        hardneg[b] = sum_gt + (float)(K - cgt_t) * __uint_as_float(kth);
    }
}

// ---------------------------------------------------------------------------
// Kernel D: final scalar combine.
// ---------------------------------------------------------------------------
__global__ void final_kernel(const int* __restrict__ npos,
                             const float* __restrict__ hardneg,
                             const float* __restrict__ totals,
                             float* __restrict__ out)
{
    const int tid = threadIdx.x;
    int np = (tid < BB) ? npos[tid] : 0;
    float hn = (tid < BB) ? hardneg[tid] : 0.0f;
    for (int off = 32; off > 0; off >>= 1) {
        np += __shfl_xor(np, off);
        hn += __shfl_xor(hn, off);
    }
    if (tid == 0) {
        float npt = (float)np;
        out[0] = (hn + totals[0]) / npt + totals[1] / (4.0f * npt);
    }
}

extern "C" void kernel_launch(void* const* d_in, const int* in_sizes, int n_in,
                              void* d_out, int out_size, void* d_ws, size_t ws_size,
                              hipStream_t stream) {
    (void)in_sizes; (void)n_in; (void)out_size; (void)ws_size;
    const float* plocs  = (const float*)d_in[0];
    const float* logits = (const float*)d_in[1];
    const float* boxes  = (const float*)d_in[2];
    const int*   labels = (const int*)d_in[3];
    const float* priors = (const float*)d_in[4];
    float* out = (float*)d_out;

    char* ws = (char*)d_ws;
    float* ovl     = (float*)ws; ws += (size_t)BB * PP * 4;
    int*   obj     = (int*)ws;   ws += (size_t)BB * PP * 4;
    float* neg     = (float*)ws; ws += (size_t)BB * PP * 4;
    int*   npos    = (int*)ws;   ws += BB * 4;
    float* hardneg = (float*)ws; ws += BB * 4;
    float* totals  = (float*)ws; ws += 2 * 4;
    unsigned long long* keys = (unsigned long long*)ws; ws += BB * MM * 8;

    // zero npos + hardneg + totals + keys (contiguous, 8B-aligned start not
    // required for memset)
    hipMemsetAsync(npos, 0, BB * 4 + BB * 4 + 2 * 4 + BB * MM * 8, stream);

    match_part_kernel<<<BB * CHUNKS, 256, 0, stream>>>(boxes, priors, ovl, obj, keys);
    force_match_kernel<<<1, 64, 0, stream>>>(keys, ovl, obj);

    conf_kernel<<<CONF_BLOCKS, 256, 0, stream>>>(logits, plocs, boxes, labels, priors,
                                                 ovl, obj, neg, npos, totals);

    topk_kernel<<<BB, 1024, 0, stream>>>(neg, npos, hardneg);

    final_kernel<<<1, 64, 0, stream>>>(npos, hardneg, totals, out);
}

// Round 3
// 79.377 us; speedup vs baseline: 5.2373x; 4.1545x over previous
//
#include <hip/hip_runtime.h>
#include <math.h>

#define BB 32
#define PP 8732
#define MM 16
#define NC 81
#define THRESH 0.5f
#define NPR 3
#define CHUNKS 16
#define CHUNK ((PP + CHUNKS - 1) / CHUNKS)   // 546
#define SBLK 64                              // conf blocks per image

// ---------------------------------------------------------------------------
// Kernel A1: partitioned matching. grid = BB*CHUNKS blocks; block (b,c) handles
// priors [c*CHUNK, ...) of image b: writes per-prior best overlap/object, and
// contributes to per-object best-prior via packed atomicMax key:
//   key = (iou_bits << 32) | (0x7FFFFFFF - p)
// (iou >= 0 so float bits are monotonic; ties on iou -> larger key = smaller p
//  = first-occurrence argmax, matching jnp.argmax.)  ~512 atomics total, all
// to distinct [B,M] slots -> negligible contention.
// ---------------------------------------------------------------------------
__global__ void __launch_bounds__(256) match_part_kernel(
    const float* __restrict__ boxes,   // [B,M,4] xy
    const float* __restrict__ priors,  // [P,4] cxcy
    float* __restrict__ ovl,           // [B,P]
    int* __restrict__ obj,             // [B,P]
    unsigned long long* __restrict__ keys)  // [B,M]
{
    const int b = blockIdx.x / CHUNKS;
    const int c = blockIdx.x % CHUNKS;
    const int tid = threadIdx.x;
    __shared__ float s_box[MM][4];
    __shared__ float s_area[MM];
    __shared__ float s_bv[4 * MM];
    __shared__ int   s_bi[4 * MM];

    if (tid < MM * 4) ((float*)s_box)[tid] = boxes[b * MM * 4 + tid];
    __syncthreads();
    if (tid < MM)
        s_area[tid] = (s_box[tid][2] - s_box[tid][0]) * (s_box[tid][3] - s_box[tid][1]);
    __syncthreads();

    float bestv[MM];
    int   bestp[MM];
#pragma unroll
    for (int m = 0; m < MM; ++m) { bestv[m] = -1.0f; bestp[m] = 0; }

    const int p0 = c * CHUNK;
    const int p1 = (p0 + CHUNK < PP) ? (p0 + CHUNK) : PP;
    for (int p = p0 + tid; p < p1; p += 256) {
        const float4 pr = ((const float4*)priors)[p];
        float px0 = pr.x - pr.z * 0.5f, py0 = pr.y - pr.w * 0.5f;
        float px1 = pr.x + pr.z * 0.5f, py1 = pr.y + pr.w * 0.5f;
        float parea = (px1 - px0) * (py1 - py0);
        float bv = -1.0f; int bm = 0;
#pragma unroll
        for (int m = 0; m < MM; ++m) {
            float lx = fmaxf(s_box[m][0], px0);
            float ly = fmaxf(s_box[m][1], py0);
            float rx = fminf(s_box[m][2], px1);
            float ry = fminf(s_box[m][3], py1);
            float w = fmaxf(rx - lx, 0.0f);
            float h = fmaxf(ry - ly, 0.0f);
            float inter = w * h;
            float iou = inter / (s_area[m] + parea - inter);
            if (iou > bv) { bv = iou; bm = m; }                   // first occurrence over m
            if (iou > bestv[m]) { bestv[m] = iou; bestp[m] = p; } // p ascending per thread
        }
        ovl[b * PP + p] = bv;
        obj[b * PP + p] = bm;
    }

    const int lane = tid & 63, wid = tid >> 6;
#pragma unroll
    for (int m = 0; m < MM; ++m) {
        float v = bestv[m]; int i = bestp[m];
        for (int off = 32; off > 0; off >>= 1) {
            float ov = __shfl_xor(v, off);
            int   oi = __shfl_xor(i, off);
            if (ov > v || (ov == v && oi < i)) { v = ov; i = oi; }
        }
        if (lane == 0) { s_bv[wid * MM + m] = v; s_bi[wid * MM + m] = i; }
    }
    __syncthreads();

    if (tid == 0) {
        for (int m = 0; m < MM; ++m) {
            float v = s_bv[m]; int i = s_bi[m];
            for (int w = 1; w < 4; ++w) {
                float ov = s_bv[w * MM + m]; int oi = s_bi[w * MM + m];
                if (ov > v || (ov == v && oi < i)) { v = ov; i = oi; }
            }
            if (v < 0.0f) v = 0.0f;  // keep bits nonneg/monotonic
            unsigned long long key =
                ((unsigned long long)__float_as_uint(v) << 32) |
                (unsigned long long)(0x7FFFFFFFu - (unsigned)i);
            atomicMax(&keys[b * MM + m], key);
        }
    }
}

// ---------------------------------------------------------------------------
// Kernel A2: force-match scatter. One thread per image, m ascending so that
// duplicate best-priors resolve last-write-wins (numpy scatter semantics).
// ---------------------------------------------------------------------------
__global__ void force_match_kernel(const unsigned long long* __restrict__ keys,
                                   float* __restrict__ ovl, int* __restrict__ obj)
{
    const int b = threadIdx.x;
    if (b < BB) {
        for (int m = 0; m < MM; ++m) {
            unsigned long long key = keys[b * MM + m];
            int p = (int)(0x7FFFFFFFu - (unsigned)(key & 0xFFFFFFFFull));
            obj[b * PP + p] = m;
            ovl[b * PP + p] = 1.0f;
        }
    }
}

// ---------------------------------------------------------------------------
// Kernel B: per-image blocks (block = b*SBLK+s), 16 lanes per row. NO global
// atomics: per-thread register accumulation -> block reduce -> per-block
// partials (cnt, conf-sum, loc-sum).
// ---------------------------------------------------------------------------
__global__ void __launch_bounds__(256) conf_kernel(
    const float* __restrict__ logits,  // [B,P,81]
    const float* __restrict__ plocs,   // [B,P,4]
    const float* __restrict__ boxes,   // [B,M,4] xy
    const int*   __restrict__ labels,  // [B,M]
    const float* __restrict__ priors,  // [P,4] cxcy
    const float* __restrict__ ovl,     // [B,P]
    const int*   __restrict__ obj,     // [B,P]
    float* __restrict__ neg,           // [B,P]
    int*   __restrict__ cnt_part,      // [BB*SBLK]
    float* __restrict__ conf_part,     // [BB*SBLK]
    float* __restrict__ loc_part)      // [BB*SBLK]
{
    const int tid = threadIdx.x;
    const int lane = tid & 63;
    const int g = lane >> 4;          // row group within wave (0..3)
    const int i = lane & 15;          // lane within group
    const int b = blockIdx.x / SBLK;
    const int s = blockIdx.x % SBLK;
    const int w0 = s * 4 + (tid >> 6);
    const int GPI = PP / 4;           // 2183

    int   pcnt = 0;
    float pconf = 0.0f, ploc = 0.0f;

    for (int wi = w0; wi < GPI; wi += SBLK * 4) {
        const int rp = wi * 4 + g;               // row within image
        const int r = b * PP + rp;               // global row
        // match results early so the dependent labels load overlaps softmax
        const float ov = ovl[r];
        const int o = obj[r];
        const int lab = labels[b * MM + o];

        const size_t base = (size_t)r * NC;
        float e0 = logits[base + i];
        float e1 = logits[base + 16 + i];
        float e2 = logits[base + 32 + i];
        float e3 = logits[base + 48 + i];
        float e4 = logits[base + 64 + i];
        float e5 = (i == 0) ? logits[base + 80] : -INFINITY;

        float mx = fmaxf(fmaxf(fmaxf(e0, e1), fmaxf(e2, e3)), fmaxf(e4, e5));
#pragma unroll
        for (int off = 8; off > 0; off >>= 1) mx = fmaxf(mx, __shfl_xor(mx, off));
        float sum = __expf(e0 - mx) + __expf(e1 - mx) + __expf(e2 - mx) +
                    __expf(e3 - mx) + __expf(e4 - mx) +
                    ((i == 0) ? __expf(e5 - mx) : 0.0f);
#pragma unroll
        for (int off = 8; off > 0; off >>= 1) sum += __shfl_xor(sum, off);

        const int cls = (ov < THRESH) ? 0 : lab;
        const int k = cls >> 4, ci = cls & 15;   // cls==80 -> k=5,ci=0 (lane 0 holds e5)
        float ek = (k == 0) ? e0 : (k == 1) ? e1 : (k == 2) ? e2 :
                   (k == 3) ? e3 : (k == 4) ? e4 : e5;
        float xc = __shfl(ek, (g << 4) + ci);
        float conf = mx + __logf(sum) - xc;
        if (!isfinite(conf)) conf = 0.0f;

        if (i == 0) {
            neg[r] = (cls == 0) ? conf : 0.0f;
            if (cls != 0) {
                pcnt += 1;
                pconf += conf;
                const float4 bx = ((const float4*)boxes)[b * MM + o];
                float cx = (bx.x + bx.z) * 0.5f;
                float cy = (bx.y + bx.w) * 0.5f;
                float w4 = bx.z - bx.x;
                float h4 = bx.w - bx.y;
                const float4 pr = ((const float4*)priors)[rp];
                float g0 = (cx - pr.x) / (pr.z / 10.0f);
                float g1 = (cy - pr.y) / (pr.w / 10.0f);
                float g2 = logf(w4 / pr.z) * 5.0f;
                float g3 = logf(h4 / pr.w) * 5.0f;
                const float4 pl = ((const float4*)plocs)[r];
                ploc += fabsf(pl.x - g0) + fabsf(pl.y - g1) +
                        fabsf(pl.z - g2) + fabsf(pl.w - g3);
            }
        }
    }

    // block reduce (values only in i==0 lanes; others hold 0)
    __shared__ int   s4i[4];
    __shared__ float s4c[4], s4l[4];
#pragma unroll
    for (int off = 32; off > 0; off >>= 1) {
        pcnt  += __shfl_xor(pcnt, off);
        pconf += __shfl_xor(pconf, off);
        ploc  += __shfl_xor(ploc, off);
    }
    const int wv = tid >> 6;
    if (lane == 0) { s4i[wv] = pcnt; s4c[wv] = pconf; s4l[wv] = ploc; }
    __syncthreads();
    if (tid == 0) {
        cnt_part[blockIdx.x]  = s4i[0] + s4i[1] + s4i[2] + s4i[3];
        conf_part[blockIdx.x] = s4c[0] + s4c[1] + s4c[2] + s4c[3];
        loc_part[blockIdx.x]  = s4l[0] + s4l[1] + s4l[2] + s4l[3];
    }
}

// ---------------------------------------------------------------------------
// Kernel C: per-image exact top-K sum via bit-pattern bisection; values staged
// in REGISTERS (9 per thread, 1024 threads). K derived from cnt partials.
// ---------------------------------------------------------------------------
#define TPK 1024
#define VPT ((PP + TPK - 1) / TPK)   // 9

__global__ void __launch_bounds__(TPK) topk_kernel(
    const float* __restrict__ neg, const int* __restrict__ cnt_part,
    float* __restrict__ hardneg)
{
    const int b = blockIdx.x;
    const int tid = threadIdx.x;
    const int lane = tid & 63, wid = tid >> 6;
    __shared__ int s16i[16];
    __shared__ float s16f[16];
    __shared__ int s_k;

    // K = 3 * npos(image b), from the 64 per-block count partials
    if (tid < 64) {
        int c = cnt_part[b * SBLK + tid];
#pragma unroll
        for (int off = 32; off > 0; off >>= 1) c += __shfl_xor(c, off);
        if (tid == 0) s_k = NPR * c;
    }

    unsigned v[VPT];
#pragma unroll
    for (int j = 0; j < VPT; ++j) {
        int p = tid + j * TPK;
        v[j] = (p < PP) ? __float_as_uint(neg[b * PP + p]) : 0u;
    }
    __syncthreads();

    int K = s_k;
    if (K > PP) K = PP;
    if (K <= 0) { if (tid == 0) hardneg[b] = 0.0f; return; }

    unsigned lo = 0u, hi = 0x7fffffffu;
    while (lo < hi) {
        unsigned mid = lo + ((hi - lo + 1u) >> 1);
        int cnt = 0;
#pragma unroll
        for (int j = 0; j < VPT; ++j) cnt += (v[j] >= mid);
#pragma unroll
        for (int off = 32; off > 0; off >>= 1) cnt += __shfl_xor(cnt, off);
        if (lane == 0) s16i[wid] = cnt;
        __syncthreads();
        int total = 0;
#pragma unroll
        for (int j = 0; j < 16; ++j) total += s16i[j];
        __syncthreads();
        if (total >= K) lo = mid; else hi = mid - 1u;
    }
    const unsigned kth = lo;

    int cgt = 0; float sgt = 0.0f;
#pragma unroll
    for (int j = 0; j < VPT; ++j) {
        if (v[j] > kth) { cgt++; sgt += __uint_as_float(v[j]); }
    }
#pragma unroll
    for (int off = 32; off > 0; off >>= 1) {
        cgt += __shfl_xor(cgt, off);
        sgt += __shfl_xor(sgt, off);
    }
    if (lane == 0) { s16i[wid] = cgt; s16f[wid] = sgt; }
    __syncthreads();
    if (tid == 0) {
        int cgt_t = 0; float sum_gt = 0.0f;
#pragma unroll
        for (int j = 0; j < 16; ++j) { cgt_t += s16i[j]; sum_gt += s16f[j]; }
        hardneg[b] = sum_gt + (float)(K - cgt_t) * __uint_as_float(kth);
    }
}

// ---------------------------------------------------------------------------
// Kernel D: final scalar combine; reduces the 2048 per-block partials + 32
// per-image hard-negative sums.
// ---------------------------------------------------------------------------
__global__ void __launch_bounds__(256) final_kernel(
    const int* __restrict__ cnt_part,
    const float* __restrict__ conf_part,
    const float* __restrict__ loc_part,
    const float* __restrict__ hardneg,
    float* __restrict__ out)
{
    const int tid = threadIdx.x;
    const int lane = tid & 63, wid = tid >> 6;
    __shared__ int s4i[4];
    __shared__ float s4c[4], s4l[4], s4h[4];

    int np = 0; float cf = 0.0f, lc = 0.0f, hn = 0.0f;
    for (int j = tid; j < BB * SBLK; j += 256) {
        np += cnt_part[j];
        cf += conf_part[j];
        lc += loc_part[j];
    }
    if (tid < BB) hn = hardneg[tid];

#pragma unroll
    for (int off = 32; off > 0; off >>= 1) {
        np += __shfl_xor(np, off);
        cf += __shfl_xor(cf, off);
        lc += __shfl_xor(lc, off);
        hn += __shfl_xor(hn, off);
    }
    if (lane == 0) { s4i[wid] = np; s4c[wid] = cf; s4l[wid] = lc; s4h[wid] = hn; }
    __syncthreads();
    if (tid == 0) {
        float npt = (float)(s4i[0] + s4i[1] + s4i[2] + s4i[3]);
        float cft = s4c[0] + s4c[1] + s4c[2] + s4c[3];
        float lct = s4l[0] + s4l[1] + s4l[2] + s4l[3];
        float hnt = s4h[0] + s4h[1] + s4h[2] + s4h[3];
        out[0] = (hnt + cft) / npt + lct / (4.0f * npt);
    }
}

extern "C" void kernel_launch(void* const* d_in, const int* in_sizes, int n_in,
                              void* d_out, int out_size, void* d_ws, size_t ws_size,
                              hipStream_t stream) {
    (void)in_sizes; (void)n_in; (void)out_size; (void)ws_size;
    const float* plocs  = (const float*)d_in[0];
    const float* logits = (const float*)d_in[1];
    const float* boxes  = (const float*)d_in[2];
    const int*   labels = (const int*)d_in[3];
    const float* priors = (const float*)d_in[4];
    float* out = (float*)d_out;

    char* ws = (char*)d_ws;
    float* ovl      = (float*)ws; ws += (size_t)BB * PP * 4;
    int*   obj      = (int*)ws;   ws += (size_t)BB * PP * 4;
    float* neg      = (float*)ws; ws += (size_t)BB * PP * 4;
    unsigned long long* keys = (unsigned long long*)ws; ws += BB * MM * 8;
    int*   cnt_part  = (int*)ws;   ws += BB * SBLK * 4;
    float* conf_part = (float*)ws; ws += BB * SBLK * 4;
    float* loc_part  = (float*)ws; ws += BB * SBLK * 4;
    float* hardneg   = (float*)ws; ws += BB * 4;

    // keys must be zeroed every call (ws is poisoned 0xAA before timing and
    // atomicMax is sticky across replays otherwise)
    hipMemsetAsync(keys, 0, BB * MM * 8, stream);

    match_part_kernel<<<BB * CHUNKS, 256, 0, stream>>>(boxes, priors, ovl, obj, keys);
    force_match_kernel<<<1, 64, 0, stream>>>(keys, ovl, obj);

    conf_kernel<<<BB * SBLK, 256, 0, stream>>>(logits, plocs, boxes, labels, priors,
                                               ovl, obj, neg,
                                               cnt_part, conf_part, loc_part);

    topk_kernel<<<BB, TPK, 0, stream>>>(neg, cnt_part, hardneg);

    final_kernel<<<1, 256, 0, stream>>>(cnt_part, conf_part, loc_part, hardneg, out);
}

// Round 4
// 75.234 us; speedup vs baseline: 5.5256x; 1.0551x over previous
//
#include <hip/hip_runtime.h>
#include <math.h>

#define BB 32
#define PP 8732
#define MM 16
#define NC 81
#define THRESH 0.5f
#define NPR 3
#define CHUNKS 16
#define CHUNK ((PP + CHUNKS - 1) / CHUNKS)   // 546
#define SBLK 64                              // conf blocks per image

// ---------------------------------------------------------------------------
// Kernel A1: partitioned matching. grid = BB*CHUNKS blocks; block (b,c) handles
// priors [c*CHUNK, ...) of image b: writes per-prior best overlap/object, and
// writes its per-chunk best-prior-per-object to its OWN slot keys_part[b][c][m]
// (packed key = (iou_bits << 32) | (0x7FFFFFFF - p); iou >= 0 so float bits are
// monotonic; ties on iou -> larger key = smaller p = first-occurrence argmax,
// matching jnp.argmax). Every slot written unconditionally -> no zero-init, no
// atomics, deterministic across graph replays.
// ---------------------------------------------------------------------------
__global__ void __launch_bounds__(256) match_part_kernel(
    const float* __restrict__ boxes,   // [B,M,4] xy
    const float* __restrict__ priors,  // [P,4] cxcy
    float* __restrict__ ovl,           // [B,P]
    int* __restrict__ obj,             // [B,P]
    unsigned long long* __restrict__ keys_part)  // [B,CHUNKS,M]
{
    const int b = blockIdx.x / CHUNKS;
    const int c = blockIdx.x % CHUNKS;
    const int tid = threadIdx.x;
    __shared__ float s_box[MM][4];
    __shared__ float s_area[MM];
    __shared__ float s_bv[4 * MM];
    __shared__ int   s_bi[4 * MM];

    if (tid < MM * 4) ((float*)s_box)[tid] = boxes[b * MM * 4 + tid];
    __syncthreads();
    if (tid < MM)
        s_area[tid] = (s_box[tid][2] - s_box[tid][0]) * (s_box[tid][3] - s_box[tid][1]);
    __syncthreads();

    float bestv[MM];
    int   bestp[MM];
#pragma unroll
    for (int m = 0; m < MM; ++m) { bestv[m] = -1.0f; bestp[m] = 0; }

    const int p0 = c * CHUNK;
    const int p1 = (p0 + CHUNK < PP) ? (p0 + CHUNK) : PP;
    for (int p = p0 + tid; p < p1; p += 256) {
        const float4 pr = ((const float4*)priors)[p];
        float px0 = pr.x - pr.z * 0.5f, py0 = pr.y - pr.w * 0.5f;
        float px1 = pr.x + pr.z * 0.5f, py1 = pr.y + pr.w * 0.5f;
        float parea = (px1 - px0) * (py1 - py0);
        float bv = -1.0f; int bm = 0;
#pragma unroll
        for (int m = 0; m < MM; ++m) {
            float lx = fmaxf(s_box[m][0], px0);
            float ly = fmaxf(s_box[m][1], py0);
            float rx = fminf(s_box[m][2], px1);
            float ry = fminf(s_box[m][3], py1);
            float w = fmaxf(rx - lx, 0.0f);
            float h = fmaxf(ry - ly, 0.0f);
            float inter = w * h;
            float iou = inter / (s_area[m] + parea - inter);
            if (iou > bv) { bv = iou; bm = m; }                   // first occurrence over m
            if (iou > bestv[m]) { bestv[m] = iou; bestp[m] = p; } // p ascending per thread
        }
        ovl[b * PP + p] = bv;
        obj[b * PP + p] = bm;
    }

    const int lane = tid & 63, wid = tid >> 6;
#pragma unroll
    for (int m = 0; m < MM; ++m) {
        float v = bestv[m]; int i = bestp[m];
        for (int off = 32; off > 0; off >>= 1) {
            float ov = __shfl_xor(v, off);
            int   oi = __shfl_xor(i, off);
            if (ov > v || (ov == v && oi < i)) { v = ov; i = oi; }
        }
        if (lane == 0) { s_bv[wid * MM + m] = v; s_bi[wid * MM + m] = i; }
    }
    __syncthreads();

    if (tid == 0) {
        for (int m = 0; m < MM; ++m) {
            float v = s_bv[m]; int i = s_bi[m];
            for (int w = 1; w < 4; ++w) {
                float ov = s_bv[w * MM + m]; int oi = s_bi[w * MM + m];
                if (ov > v || (ov == v && oi < i)) { v = ov; i = oi; }
            }
            if (v < 0.0f) v = 0.0f;  // keep bits nonneg/monotonic
            keys_part[(b * CHUNKS + c) * MM + m] =
                ((unsigned long long)__float_as_uint(v) << 32) |
                (unsigned long long)(0x7FFFFFFFu - (unsigned)i);
        }
    }
}

// ---------------------------------------------------------------------------
// Kernel A2: chunk-reduce + force-match scatter. One block of 512 threads:
// thread (b,m) reduces its 16 chunk keys, then 32 threads scatter m-ascending
// (duplicate best-priors resolve last-write-wins = numpy scatter semantics).
// ---------------------------------------------------------------------------
__global__ void __launch_bounds__(512) force_match_kernel(
    const unsigned long long* __restrict__ keys_part,
    float* __restrict__ ovl, int* __restrict__ obj)
{
    __shared__ int s_p[BB * MM];
    const int tid = threadIdx.x;           // 0..511 = b*16+m
    const int b = tid >> 4, m = tid & 15;

    unsigned long long best = 0ull;
#pragma unroll
    for (int c = 0; c < CHUNKS; ++c) {
        unsigned long long k = keys_part[(b * CHUNKS + c) * MM + m];
        if (k > best) best = k;
    }
    s_p[tid] = (int)(0x7FFFFFFFu - (unsigned)(best & 0xFFFFFFFFull));
    __syncthreads();

    if (m == 0) {
        for (int mm = 0; mm < MM; ++mm) {   // m ascending: last write wins
            int p = s_p[(b << 4) + mm];
            obj[b * PP + p] = mm;
            ovl[b * PP + p] = 1.0f;
        }
    }
}

// ---------------------------------------------------------------------------
// Kernel B: per-image blocks (block = b*SBLK+s), 16 lanes per row. NO global
// atomics: per-thread register accumulation -> block reduce -> per-block
// partials (cnt, conf-sum, loc-sum).
// ---------------------------------------------------------------------------
__global__ void __launch_bounds__(256) conf_kernel(
    const float* __restrict__ logits,  // [B,P,81]
    const float* __restrict__ plocs,   // [B,P,4]
    const float* __restrict__ boxes,   // [B,M,4] xy
    const int*   __restrict__ labels,  // [B,M]
    const float* __restrict__ priors,  // [P,4] cxcy
    const float* __restrict__ ovl,     // [B,P]
    const int*   __restrict__ obj,     // [B,P]
    float* __restrict__ neg,           // [B,P]
    int*   __restrict__ cnt_part,      // [BB*SBLK]
    float* __restrict__ conf_part,     // [BB*SBLK]
    float* __restrict__ loc_part)      // [BB*SBLK]
{
    const int tid = threadIdx.x;
    const int lane = tid & 63;
    const int g = lane >> 4;          // row group within wave (0..3)
    const int i = lane & 15;          // lane within group
    const int b = blockIdx.x / SBLK;
    const int s = blockIdx.x % SBLK;
    const int w0 = s * 4 + (tid >> 6);
    const int GPI = PP / 4;           // 2183

    int   pcnt = 0;
    float pconf = 0.0f, ploc = 0.0f;

    for (int wi = w0; wi < GPI; wi += SBLK * 4) {
        const int rp = wi * 4 + g;               // row within image
        const int r = b * PP + rp;               // global row
        const float ov = ovl[r];
        const int o = obj[r];
        const int lab = labels[b * MM + o];

        const size_t base = (size_t)r * NC;
        float e0 = logits[base + i];
        float e1 = logits[base + 16 + i];
        float e2 = logits[base + 32 + i];
        float e3 = logits[base + 48 + i];
        float e4 = logits[base + 64 + i];
        float e5 = (i == 0) ? logits[base + 80] : -INFINITY;

        float mx = fmaxf(fmaxf(fmaxf(e0, e1), fmaxf(e2, e3)), fmaxf(e4, e5));
#pragma unroll
        for (int off = 8; off > 0; off >>= 1) mx = fmaxf(mx, __shfl_xor(mx, off));
        float sum = __expf(e0 - mx) + __expf(e1 - mx) + __expf(e2 - mx) +
                    __expf(e3 - mx) + __expf(e4 - mx) +
                    ((i == 0) ? __expf(e5 - mx) : 0.0f);
#pragma unroll
        for (int off = 8; off > 0; off >>= 1) sum += __shfl_xor(sum, off);

        const int cls = (ov < THRESH) ? 0 : lab;
        const int k = cls >> 4, ci = cls & 15;   // cls==80 -> k=5,ci=0 (lane 0 holds e5)
        float ek = (k == 0) ? e0 : (k == 1) ? e1 : (k == 2) ? e2 :
                   (k == 3) ? e3 : (k == 4) ? e4 : e5;
        float xc = __shfl(ek, (g << 4) + ci);
        float conf = mx + __logf(sum) - xc;
        if (!isfinite(conf)) conf = 0.0f;

        if (i == 0) {
            neg[r] = (cls == 0) ? conf : 0.0f;
            if (cls != 0) {
                pcnt += 1;
                pconf += conf;
                const float4 bx = ((const float4*)boxes)[b * MM + o];
                float cx = (bx.x + bx.z) * 0.5f;
                float cy = (bx.y + bx.w) * 0.5f;
                float w4 = bx.z - bx.x;
                float h4 = bx.w - bx.y;
                const float4 pr = ((const float4*)priors)[rp];
                float g0 = (cx - pr.x) / (pr.z / 10.0f);
                float g1 = (cy - pr.y) / (pr.w / 10.0f);
                float g2 = logf(w4 / pr.z) * 5.0f;
                float g3 = logf(h4 / pr.w) * 5.0f;
                const float4 pl = ((const float4*)plocs)[r];
                ploc += fabsf(pl.x - g0) + fabsf(pl.y - g1) +
                        fabsf(pl.z - g2) + fabsf(pl.w - g3);
            }
        }
    }

    __shared__ int   s4i[4];
    __shared__ float s4c[4], s4l[4];
#pragma unroll
    for (int off = 32; off > 0; off >>= 1) {
        pcnt  += __shfl_xor(pcnt, off);
        pconf += __shfl_xor(pconf, off);
        ploc  += __shfl_xor(ploc, off);
    }
    const int wv = tid >> 6;
    if (lane == 0) { s4i[wv] = pcnt; s4c[wv] = pconf; s4l[wv] = ploc; }
    __syncthreads();
    if (tid == 0) {
        cnt_part[blockIdx.x]  = s4i[0] + s4i[1] + s4i[2] + s4i[3];
        conf_part[blockIdx.x] = s4c[0] + s4c[1] + s4c[2] + s4c[3];
        loc_part[blockIdx.x]  = s4l[0] + s4l[1] + s4l[2] + s4l[3];
    }
}

// ---------------------------------------------------------------------------
// Kernel C: per-image exact top-K sum via bit-pattern bisection; values staged
// in REGISTERS (9 per thread, 1024 threads). K derived from cnt partials.
// ---------------------------------------------------------------------------
#define TPK 1024
#define VPT ((PP + TPK - 1) / TPK)   // 9

__global__ void __launch_bounds__(TPK) topk_kernel(
    const float* __restrict__ neg, const int* __restrict__ cnt_part,
    float* __restrict__ hardneg)
{
    const int b = blockIdx.x;
    const int tid = threadIdx.x;
    const int lane = tid & 63, wid = tid >> 6;
    __shared__ int s16i[16];
    __shared__ float s16f[16];
    __shared__ int s_k;

    if (tid < 64) {
        int c = cnt_part[b * SBLK + tid];
#pragma unroll
        for (int off = 32; off > 0; off >>= 1) c += __shfl_xor(c, off);
        if (tid == 0) s_k = NPR * c;
    }

    unsigned v[VPT];
#pragma unroll
    for (int j = 0; j < VPT; ++j) {
        int p = tid + j * TPK;
        v[j] = (p < PP) ? __float_as_uint(neg[b * PP + p]) : 0u;
    }
    __syncthreads();

    int K = s_k;
    if (K > PP) K = PP;
    if (K <= 0) { if (tid == 0) hardneg[b] = 0.0f; return; }

    unsigned lo = 0u, hi = 0x7fffffffu;
    while (lo < hi) {
        unsigned mid = lo + ((hi - lo + 1u) >> 1);
        int cnt = 0;
#pragma unroll
        for (int j = 0; j < VPT; ++j) cnt += (v[j] >= mid);
#pragma unroll
        for (int off = 32; off > 0; off >>= 1) cnt += __shfl_xor(cnt, off);
        if (lane == 0) s16i[wid] = cnt;
        __syncthreads();
        int total = 0;
#pragma unroll
        for (int j = 0; j < 16; ++j) total += s16i[j];
        __syncthreads();
        if (total >= K) lo = mid; else hi = mid - 1u;
    }
    const unsigned kth = lo;

    int cgt = 0; float sgt = 0.0f;
#pragma unroll
    for (int j = 0; j < VPT; ++j) {
        if (v[j] > kth) { cgt++; sgt += __uint_as_float(v[j]); }
    }
#pragma unroll
    for (int off = 32; off > 0; off >>= 1) {
        cgt += __shfl_xor(cgt, off);
        sgt += __shfl_xor(sgt, off);
    }
    if (lane == 0) { s16i[wid] = cgt; s16f[wid] = sgt; }
    __syncthreads();
    if (tid == 0) {
        int cgt_t = 0; float sum_gt = 0.0f;
#pragma unroll
        for (int j = 0; j < 16; ++j) { cgt_t += s16i[j]; sum_gt += s16f[j]; }
        hardneg[b] = sum_gt + (float)(K - cgt_t) * __uint_as_float(kth);
    }
}

// ---------------------------------------------------------------------------
// Kernel D: final scalar combine; reduces the 2048 per-block partials + 32
// per-image hard-negative sums.
// ---------------------------------------------------------------------------
__global__ void __launch_bounds__(256) final_kernel(
    const int* __restrict__ cnt_part,
    const float* __restrict__ conf_part,
    const float* __restrict__ loc_part,
    const float* __restrict__ hardneg,
    float* __restrict__ out)
{
    const int tid = threadIdx.x;
    const int lane = tid & 63, wid = tid >> 6;
    __shared__ int s4i[4];
    __shared__ float s4c[4], s4l[4], s4h[4];

    int np = 0; float cf = 0.0f, lc = 0.0f, hn = 0.0f;
    for (int j = tid; j < BB * SBLK; j += 256) {
        np += cnt_part[j];
        cf += conf_part[j];
        lc += loc_part[j];
    }
    if (tid < BB) hn = hardneg[tid];

#pragma unroll
    for (int off = 32; off > 0; off >>= 1) {
        np += __shfl_xor(np, off);
        cf += __shfl_xor(cf, off);
        lc += __shfl_xor(lc, off);
        hn += __shfl_xor(hn, off);
    }
    if (lane == 0) { s4i[wid] = np; s4c[wid] = cf; s4l[wid] = lc; s4h[wid] = hn; }
    __syncthreads();
    if (tid == 0) {
        float npt = (float)(s4i[0] + s4i[1] + s4i[2] + s4i[3]);
        float cft = s4c[0] + s4c[1] + s4c[2] + s4c[3];
        float lct = s4l[0] + s4l[1] + s4l[2] + s4l[3];
        float hnt = s4h[0] + s4h[1] + s4h[2] + s4h[3];
        out[0] = (hnt + cft) / npt + lct / (4.0f * npt);
    }
}

extern "C" void kernel_launch(void* const* d_in, const int* in_sizes, int n_in,
                              void* d_out, int out_size, void* d_ws, size_t ws_size,
                              hipStream_t stream) {
    (void)in_sizes; (void)n_in; (void)out_size; (void)ws_size;
    const float* plocs  = (const float*)d_in[0];
    const float* logits = (const float*)d_in[1];
    const float* boxes  = (const float*)d_in[2];
    const int*   labels = (const int*)d_in[3];
    const float* priors = (const float*)d_in[4];
    float* out = (float*)d_out;

    char* ws = (char*)d_ws;
    float* ovl      = (float*)ws; ws += (size_t)BB * PP * 4;
    int*   obj      = (int*)ws;   ws += (size_t)BB * PP * 4;
    float* neg      = (float*)ws; ws += (size_t)BB * PP * 4;
    unsigned long long* keys_part = (unsigned long long*)ws; ws += (size_t)BB * CHUNKS * MM * 8;
    int*   cnt_part  = (int*)ws;   ws += BB * SBLK * 4;
    float* conf_part = (float*)ws; ws += BB * SBLK * 4;
    float* loc_part  = (float*)ws; ws += BB * SBLK * 4;
    float* hardneg   = (float*)ws; ws += BB * 4;

    // NO memset: every ws byte read by a kernel is unconditionally written
    // earlier in the same call (keys_part fully written by match_part, etc.)

    match_part_kernel<<<BB * CHUNKS, 256, 0, stream>>>(boxes, priors, ovl, obj, keys_part);
    force_match_kernel<<<1, 512, 0, stream>>>(keys_part, ovl, obj);

    conf_kernel<<<BB * SBLK, 256, 0, stream>>>(logits, plocs, boxes, labels, priors,
                                               ovl, obj, neg,
                                               cnt_part, conf_part, loc_part);

    topk_kernel<<<BB, TPK, 0, stream>>>(neg, cnt_part, hardneg);

    final_kernel<<<1, 256, 0, stream>>>(cnt_part, conf_part, loc_part, hardneg, out);
}